// Round 1
// baseline (1037.926 us; speedup 1.0000x reference)
//
#include <hip/hip_runtime.h>
#include <math.h>

// TransformerLayer fused implementation for MI355X (gfx950).
// Reference quirks kept faithful:
//  - v / attended_values are DEAD code in the reference -> Wv never touched.
//  - scores scaled by 1/sqrt(D)=1/sqrt(2048), not 1/sqrt(head_dim).
//  - x2 = LN1(x) + x  (residual added to LN output).
// Outputs (concat in d_out): out [4,1024,2048] fp32, attn_probs [4,32,1024,1024] fp32.
//
// Workspace layout (needs ~151 MB):
//  4x WT bf16 (2048x2048), h/h2/q/k/a1 bf16 (4096x2048), x2 fp32 (4096x2048).

typedef unsigned short u16;
typedef u16    u16x8  __attribute__((ext_vector_type(8)));
typedef __bf16 bf16x8 __attribute__((ext_vector_type(8)));
typedef float  f32x4  __attribute__((ext_vector_type(4)));

#define MFMA16(a, b, c) __builtin_amdgcn_mfma_f32_16x16x32_bf16((a), (b), (c), 0, 0, 0)

__device__ __forceinline__ u16 f2bf(float f) {
  unsigned u = __builtin_bit_cast(unsigned, f);
  u += 0x7fffu + ((u >> 16) & 1u);   // RNE
  return (u16)(u >> 16);
}

// ---------------------------------------------------------------------------
// Weight transpose + fp32->bf16 cast:  W[K][N] -> WT[N][K]   (K=N=2048)
// ---------------------------------------------------------------------------
__global__ __launch_bounds__(256) void transpose_cast(const float* __restrict__ W,
                                                      u16* __restrict__ WT) {
  __shared__ u16 tile[64][65];  // 65: odd-ish stride breaks bank alignment
  const int n0 = blockIdx.x * 64, k0 = blockIdx.y * 64;
  const int c = threadIdx.x & 63, rb = threadIdx.x >> 6;
#pragma unroll
  for (int i = 0; i < 16; i++) {
    int r = rb + i * 4;
    tile[r][c] = f2bf(W[(size_t)(k0 + r) * 2048 + n0 + c]);
  }
  __syncthreads();
#pragma unroll
  for (int i = 0; i < 16; i++) {
    int r = rb + i * 4;
    WT[(size_t)(n0 + r) * 2048 + k0 + c] = tile[c][r];
  }
}

// ---------------------------------------------------------------------------
// Fused: h = LN1(x); x2 = h + x; h2 = LN2(x2).  One block per row (D=2048).
// ---------------------------------------------------------------------------
__device__ __forceinline__ float block_sum(float s, float* sbuf, int tid) {
#pragma unroll
  for (int off = 32; off; off >>= 1) s += __shfl_down(s, off, 64);
  __syncthreads();                       // protect sbuf reuse across calls
  if ((tid & 63) == 0) sbuf[tid >> 6] = s;
  __syncthreads();
  return sbuf[0] + sbuf[1] + sbuf[2] + sbuf[3];
}

__global__ __launch_bounds__(256) void ln_fused(
    const float* __restrict__ x,
    const float* __restrict__ s1, const float* __restrict__ b1,
    const float* __restrict__ s2, const float* __restrict__ b2,
    u16* __restrict__ h_bf, float* __restrict__ x2o, u16* __restrict__ h2_bf) {
  __shared__ float sbuf[4];
  const int row = blockIdx.x, tid = threadIdx.x;
  const size_t rbase = (size_t)row * 2048;
  const int c = tid * 8;

  float v[8];
  *(float4*)&v[0] = *(const float4*)(x + rbase + c);
  *(float4*)&v[4] = *(const float4*)(x + rbase + c + 4);

  float s = 0.f;
#pragma unroll
  for (int i = 0; i < 8; i++) s += v[i];
  const float m1 = block_sum(s, sbuf, tid) * (1.f / 2048.f);
  float ss = 0.f;
#pragma unroll
  for (int i = 0; i < 8; i++) { float d = v[i] - m1; ss += d * d; }
  const float r1 = rsqrtf(block_sum(ss, sbuf, tid) * (1.f / 2048.f) + 1e-5f);

  float w[8], bb[8];
  *(float4*)&w[0] = *(const float4*)(s1 + c);
  *(float4*)&w[4] = *(const float4*)(s1 + c + 4);
  *(float4*)&bb[0] = *(const float4*)(b1 + c);
  *(float4*)&bb[4] = *(const float4*)(b1 + c + 4);

  float xx[8];
  u16x8 hv;
#pragma unroll
  for (int i = 0; i < 8; i++) {
    float hh = (v[i] - m1) * r1 * w[i] + bb[i];
    xx[i] = hh + v[i];
    hv[i] = f2bf(hh);
  }
  *(u16x8*)(h_bf + rbase + c) = hv;
  *(float4*)(x2o + rbase + c) = *(float4*)&xx[0];
  *(float4*)(x2o + rbase + c + 4) = *(float4*)&xx[4];

  // LN2 on xx
  s = 0.f;
#pragma unroll
  for (int i = 0; i < 8; i++) s += xx[i];
  const float m2 = block_sum(s, sbuf, tid) * (1.f / 2048.f);
  ss = 0.f;
#pragma unroll
  for (int i = 0; i < 8; i++) { float d = xx[i] - m2; ss += d * d; }
  const float r2 = rsqrtf(block_sum(ss, sbuf, tid) * (1.f / 2048.f) + 1e-5f);

  *(float4*)&w[0] = *(const float4*)(s2 + c);
  *(float4*)&w[4] = *(const float4*)(s2 + c + 4);
  *(float4*)&bb[0] = *(const float4*)(b2 + c);
  *(float4*)&bb[4] = *(const float4*)(b2 + c + 4);
#pragma unroll
  for (int i = 0; i < 8; i++) hv[i] = f2bf((xx[i] - m2) * r2 * w[i] + bb[i]);
  *(u16x8*)(h2_bf + rbase + c) = hv;
}

// ---------------------------------------------------------------------------
// bf16 MFMA GEMM: C[M=4096][N=2048] = A[4096][2048] @ BT[2048][2048]^T
// BT is the pre-transposed weight (BT[n][k] = W[k][n]), so both operands are
// k-contiguous. 128x128 block tile, BK=32, 4 waves x (4x4) 16x16x32 tiles.
// ---------------------------------------------------------------------------
template <int BIAS, int RELU, int RESID, int OUTBF>
__global__ __launch_bounds__(256) void gemm_bf16(
    const u16* __restrict__ A, const u16* __restrict__ BT,
    const float* __restrict__ bias, const float* __restrict__ resid,
    void* __restrict__ Cout) {
  constexpr int K = 2048, N = 2048;
  __shared__ u16 As[128 * 32];
  __shared__ u16 Bs[128 * 32];
  const int tid = threadIdx.x;
  const int row0 = blockIdx.y * 128, col0 = blockIdx.x * 128;
  const int wid = tid >> 6, lane = tid & 63, lr = lane & 15, quad = lane >> 4;
  const int wr0 = (wid >> 1) * 64, wc0 = (wid & 1) * 64;
  const int sr = tid >> 1, so = (tid & 1) * 16;  // staging: row, ushort offset

  f32x4 acc[4][4];
#pragma unroll
  for (int i = 0; i < 4; i++)
#pragma unroll
    for (int j = 0; j < 4; j++) acc[i][j] = (f32x4){0.f, 0.f, 0.f, 0.f};

  const u16* ga = A + (size_t)(row0 + sr) * K + so;
  const u16* gb = BT + (size_t)(col0 + sr) * K + so;
  u16* la = &As[sr * 32 + so];
  u16* lb = &Bs[sr * 32 + so];

  for (int k0 = 0; k0 < K; k0 += 32) {
    __syncthreads();
    *(u16x8*)(la) = *(const u16x8*)(ga + k0);
    *(u16x8*)(la + 8) = *(const u16x8*)(ga + k0 + 8);
    *(u16x8*)(lb) = *(const u16x8*)(gb + k0);
    *(u16x8*)(lb + 8) = *(const u16x8*)(gb + k0 + 8);
    __syncthreads();

    bf16x8 af[4], bfr[4];
#pragma unroll
    for (int i = 0; i < 4; i++)
      af[i] = *(const bf16x8*)&As[(wr0 + i * 16 + lr) * 32 + quad * 8];
#pragma unroll
    for (int j = 0; j < 4; j++)
      bfr[j] = *(const bf16x8*)&Bs[(wc0 + j * 16 + lr) * 32 + quad * 8];
#pragma unroll
    for (int i = 0; i < 4; i++)
#pragma unroll
      for (int j = 0; j < 4; j++) acc[i][j] = MFMA16(af[i], bfr[j], acc[i][j]);
  }

  // epilogue: C row = quad*4 + reg, col = lane&15 (verified gfx950 C/D layout)
#pragma unroll
  for (int i = 0; i < 4; i++) {
#pragma unroll
    for (int r = 0; r < 4; r++) {
      const int row = row0 + wr0 + i * 16 + quad * 4 + r;
#pragma unroll
      for (int j = 0; j < 4; j++) {
        const int col = col0 + wc0 + j * 16 + lr;
        float v = acc[i][j][r];
        if (BIAS) v += bias[col];
        if (RELU) v = fmaxf(v, 0.f);
        if (RESID) v += resid[(size_t)row * N + col];
        if (OUTBF)
          ((u16*)Cout)[(size_t)row * N + col] = f2bf(v);
        else
          ((float*)Cout)[(size_t)row * N + col] = v;
      }
    }
  }
}

// ---------------------------------------------------------------------------
// Attention scores + softmax, fused. One block = (b, h, 16 q-rows).
// scores[16][1024] in LDS (64 KB), probs written exactly once to d_out.
// q/k layout: [B*S][D] with col = h*64 + d  (i.e. the raw GEMM output).
// ---------------------------------------------------------------------------
__global__ __launch_bounds__(256) void attn_kernel(const u16* __restrict__ qm,
                                                   const u16* __restrict__ km,
                                                   float* __restrict__ probs) {
  __shared__ float sc[16 * 1024];
  const int tid = threadIdx.x, wid = tid >> 6, lane = tid & 63;
  const int lr = lane & 15, quad = lane >> 4;
  const int q0 = blockIdx.x * 16, h = blockIdx.y, b = blockIdx.z;

  const size_t qbase = (size_t)(b * 1024 + q0 + lr) * 2048 + h * 64 + quad * 8;
  const bf16x8 a0 = *(const bf16x8*)(qm + qbase);
  const bf16x8 a1 = *(const bf16x8*)(qm + qbase + 32);
  const float scale = 0.022097086912079608f;  // 1/sqrt(2048)

  for (int t = 0; t < 16; t++) {
    const int c0 = wid * 256 + t * 16;
    const size_t kbase = (size_t)(b * 1024 + c0 + lr) * 2048 + h * 64 + quad * 8;
    const bf16x8 b0 = *(const bf16x8*)(km + kbase);
    const bf16x8 b1 = *(const bf16x8*)(km + kbase + 32);
    f32x4 acc = (f32x4){0.f, 0.f, 0.f, 0.f};
    acc = MFMA16(a0, b0, acc);
    acc = MFMA16(a1, b1, acc);
#pragma unroll
    for (int r = 0; r < 4; r++) sc[(quad * 4 + r) * 1024 + c0 + lr] = acc[r] * scale;
  }
  __syncthreads();

#pragma unroll
  for (int rr = 0; rr < 4; rr++) {
    const int row = wid * 4 + rr;
    float vals[16];
    float mx = -1e30f;
#pragma unroll
    for (int i = 0; i < 16; i++) {
      vals[i] = sc[row * 1024 + lane + 64 * i];
      mx = fmaxf(mx, vals[i]);
    }
#pragma unroll
    for (int off = 32; off; off >>= 1) mx = fmaxf(mx, __shfl_xor(mx, off, 64));
    float sum = 0.f;
#pragma unroll
    for (int i = 0; i < 16; i++) {
      vals[i] = __expf(vals[i] - mx);
      sum += vals[i];
    }
#pragma unroll
    for (int off = 32; off; off >>= 1) sum += __shfl_xor(sum, off, 64);
    const float inv = 1.f / sum;
    float* pr = probs + (size_t)((b * 32 + h) * 1024 + q0 + row) * 1024;
#pragma unroll
    for (int i = 0; i < 16; i++) pr[lane + 64 * i] = vals[i] * inv;
  }
}

// ---------------------------------------------------------------------------
extern "C" void kernel_launch(void* const* d_in, const int* in_sizes, int n_in,
                              void* d_out, int out_size, void* d_ws, size_t ws_size,
                              hipStream_t stream) {
  const float* x = (const float*)d_in[0];
  const float* Wq = (const float*)d_in[1];
  const float* Wk = (const float*)d_in[2];
  // d_in[3] = Wv: dead in the reference (attended values are discarded)
  const float* ln1s = (const float*)d_in[4];
  const float* ln1b = (const float*)d_in[5];
  const float* ln2s = (const float*)d_in[6];
  const float* ln2b = (const float*)d_in[7];
  const float* f1w = (const float*)d_in[8];
  const float* f1b = (const float*)d_in[9];
  const float* f2w = (const float*)d_in[10];
  const float* f2b = (const float*)d_in[11];

  char* p = (char*)d_ws;
  const size_t WSZ = (size_t)2048 * 2048 * 2;   // 8 MB bf16 weight
  const size_t ASZ = (size_t)4096 * 2048 * 2;   // 16 MB bf16 activation
  u16* WqT = (u16*)p; p += WSZ;
  u16* WkT = (u16*)p; p += WSZ;
  u16* F1T = (u16*)p; p += WSZ;
  u16* F2T = (u16*)p; p += WSZ;
  u16* h_bf = (u16*)p; p += ASZ;
  u16* h2_bf = (u16*)p; p += ASZ;
  u16* q_bf = (u16*)p; p += ASZ;
  u16* k_bf = (u16*)p; p += ASZ;
  u16* a1_bf = (u16*)p; p += ASZ;
  float* x2 = (float*)p; p += (size_t)4096 * 2048 * 4;

  float* out = (float*)d_out;
  float* probs = out + (size_t)4096 * 2048;

  const dim3 tg(32, 32);
  transpose_cast<<<tg, 256, 0, stream>>>(Wq, WqT);
  transpose_cast<<<tg, 256, 0, stream>>>(Wk, WkT);
  transpose_cast<<<tg, 256, 0, stream>>>(f1w, F1T);
  transpose_cast<<<tg, 256, 0, stream>>>(f2w, F2T);

  ln_fused<<<4096, 256, 0, stream>>>(x, ln1s, ln1b, ln2s, ln2b, h_bf, x2, h2_bf);

  const dim3 gg(16, 32);
  gemm_bf16<0, 0, 0, 1><<<gg, 256, 0, stream>>>(h_bf, WqT, nullptr, nullptr, q_bf);
  gemm_bf16<0, 0, 0, 1><<<gg, 256, 0, stream>>>(h_bf, WkT, nullptr, nullptr, k_bf);

  attn_kernel<<<dim3(64, 32, 4), 256, 0, stream>>>(q_bf, k_bf, probs);

  gemm_bf16<1, 1, 0, 1><<<gg, 256, 0, stream>>>(h2_bf, F1T, f1b, nullptr, a1_bf);
  gemm_bf16<1, 0, 1, 0><<<gg, 256, 0, stream>>>(a1_bf, F2T, f2b, x2, out);
}